// Round 8
// baseline (175.146 us; speedup 1.0000x reference)
//
#include <hip/hip_runtime.h>

#define NB 8
#define NC 128
#define NM 4096
#define FRAG 512   // shorts per (tile,ks) fragment block: 64 lanes x 8

typedef __attribute__((ext_vector_type(8))) short short8;
typedef __attribute__((ext_vector_type(4))) float floatx4;

#define MFMA(a, b, c) __builtin_amdgcn_mfma_f32_16x16x32_bf16(a, b, c, 0, 0, 0)
#define EXP2F(x) __builtin_amdgcn_exp2f(x)

union S8U { short8 v; uint2 u2[2]; };

__device__ __forceinline__ unsigned pack2bf(float a, float b) {
    unsigned ua = __float_as_uint(a);
    unsigned ub = __float_as_uint(b);
    ua += 0x7fffu + ((ua >> 16) & 1u);
    ub += 0x7fffu + ((ub >> 16) & 1u);
    return (ua >> 16) | (ub & 0xffff0000u);
}

// Single-instruction packed f32->bf16 (RNE), same rounding as pack2bf.
__device__ __forceinline__ unsigned cvt_pk_bf16(float a, float b) {
    unsigned r;
    asm("v_cvt_pk_bf16_f32 %0, %1, %2" : "=v"(r) : "v"(a), "v"(b));
    return r;
}

// QK softmax scale folded into fX: sqrt(2^-3.5 * log2(e)); RS = 1/SF.
__constant__ float SF_C = 0.35712442f;
__constant__ float RS_C = 2.8001530f;

// ---------------------------------------------------------------------------
// Fragment-order layouts (one contiguous 1024B chunk per wave fragment load):
//   fX[b][mt(256)][ks(4)][lane(64)][8] : lane l=(lq*16+lm) holds
//       f-row (mt*16+lm), cols ks*32+lq*8..+7, scaled by SF, bf16.
//   gX[b][nblk(32)][ot(8)][k2(4)][lane(64)][8] : lane l holds
//       g-row o=ot*16+lm, n-slots PERMUTED by pi(lq,j) = (j<4 ? 4lq+j
//       : 16+4lq+j-4) within each 32-col chunk, matching the in-register
//       P fragment produced by QK+exp2+cvt_pk (zero-shuffle PV).
// ---------------------------------------------------------------------------

// P1: fX from f (transpose + scale + bf16 + fragment order)
__global__ __launch_bounds__(256) void k_prep_f(
    const float* __restrict__ f, unsigned short* __restrict__ fX)
{
    __shared__ float Ls[128][65];
    const int tid = threadIdx.x;
    const int b   = blockIdx.x & 7;
    const int m0  = (blockIdx.x >> 3) * 64;
    const float* fb = f + (size_t)b * NC * NM;
    #pragma unroll
    for (int k = 0; k < 32; ++k) {
        int idx = tid + k * 256;
        int c = idx >> 6, mm = idx & 63;
        Ls[c][mm] = fb[(size_t)c * NM + m0 + mm];
    }
    __syncthreads();
    const float sf = SF_C;
    const int m  = tid >> 2;
    const int ks = tid & 3;
    const int ch = ks * 32;
    unsigned pk[16];
    #pragma unroll
    for (int i = 0; i < 16; ++i)
        pk[i] = pack2bf(Ls[ch + 2 * i][m] * sf, Ls[ch + 2 * i + 1][m] * sf);
    const int Mg  = m0 + m;
    const int mt  = Mg >> 4;
    const int lmm = Mg & 15;
    unsigned short* dst = fX + ((size_t)b * 256 + mt) * 4 * FRAG + ks * FRAG;
    #pragma unroll
    for (int q = 0; q < 4; ++q)
        *(uint4*)(dst + (q * 16 + lmm) * 8) =
            make_uint4(pk[4 * q], pk[4 * q + 1], pk[4 * q + 2], pk[4 * q + 3]);
}

// ---------------------------------------------------------------------------
// P2 (MFMA): gX = bf16( (w1a*RS) . fX ) in fragment order with pi-permuted
// n-slots (see above). grid 256 = b(8) x nblk(32); 4 waves.
// ---------------------------------------------------------------------------
__global__ __launch_bounds__(256) void k_prep_g(
    const unsigned short* __restrict__ fX, const float* __restrict__ w1,
    unsigned short* __restrict__ gX)
{
    __shared__ unsigned short gt[128][136];   // [o][n-local]
    const int tid = threadIdx.x;
    const int wv  = tid >> 6;
    const int l   = tid & 63;
    const int lm  = l & 15;
    const int lq  = l >> 4;
    const int b    = blockIdx.x & 7;
    const int nblk = blockIdx.x >> 3;

    const float rs = RS_C;

    short8 wf2[2][4];
    #pragma unroll
    for (int j = 0; j < 2; ++j) {
        const int o = (wv * 2 + j) * 16 + lm;
        #pragma unroll
        for (int ks = 0; ks < 4; ++ks) {
            const float* wp = w1 + (size_t)o * (2 * NC) + ks * 32 + lq * 8;
            S8U t;
            t.u2[0] = make_uint2(pack2bf(wp[0] * rs, wp[1] * rs),
                                 pack2bf(wp[2] * rs, wp[3] * rs));
            t.u2[1] = make_uint2(pack2bf(wp[4] * rs, wp[5] * rs),
                                 pack2bf(wp[6] * rs, wp[7] * rs));
            wf2[j][ks] = t.v;
        }
    }

    const unsigned short* fXb = fX + (size_t)b * NM * NC;
    #pragma unroll 2
    for (int nt = 0; nt < 8; ++nt) {
        short8 af[4];
        #pragma unroll
        for (int ks = 0; ks < 4; ++ks)
            af[ks] = *(const short8*)
                (fXb + (size_t)(nblk * 8 + nt) * 4 * FRAG + ks * FRAG + l * 8);
        #pragma unroll
        for (int j = 0; j < 2; ++j) {
            floatx4 D = {0.f, 0.f, 0.f, 0.f};
            #pragma unroll
            for (int ks = 0; ks < 4; ++ks)
                D = MFMA(af[ks], wf2[j][ks], D);
            *(uint2*)&gt[(wv * 2 + j) * 16 + lm][nt * 16 + lq * 4] =
                make_uint2(pack2bf(D[0], D[1]), pack2bf(D[2], D[3]));
        }
    }
    __syncthreads();

    // pi-permuted fragment store: lane (lq,lm) reg j holds
    // g[o][k2*32 + pi(lq,j)]; pi j<4 -> 4lq+j, j>=4 -> 16+4lq+(j-4).
    #pragma unroll
    for (int j = 0; j < 2; ++j) {
        const int ot = wv * 2 + j;
        #pragma unroll
        for (int k2 = 0; k2 < 4; ++k2) {
            uint2 lo = *(const uint2*)&gt[ot * 16 + lm][k2 * 32 + lq * 4];
            uint2 hi = *(const uint2*)&gt[ot * 16 + lm][k2 * 32 + 16 + lq * 4];
            *(uint4*)(gX + (((size_t)b * 32 + nblk) * 8 + ot) * 4 * FRAG
                      + k2 * FRAG + l * 8) = make_uint4(lo.x, lo.y, hi.x, hi.y);
        }
    }
}

// ---------------------------------------------------------------------------
// Main: barrier-free MFMA flash attention + fused cls head.
// 512 threads = 8 waves: h = w>>2 (m-half: 32 rows), q = w&3 (n-chunk).
// Per iter (TN=128): wave (h,q) computes QK for ktiles 8*it+2q, +1 (its own
// 32 n), softmax-exps in-register, packs P via cvt_pk into the PV A-fragment
// DIRECTLY (gX n-slots pre-permuted by pi), and accumulates u[2mt][8ot] over
// its n-slice. NO LDS, NO barrier in the loop. Epilogue: lane-preserving
// cross-wave u reduction through LDS (identical fragment layouts), then the
// fused head per (half, o-slice). grid 512 = b(8) x mblock(64).
// ---------------------------------------------------------------------------
__global__ __launch_bounds__(512, 2) void k_attn(
    const unsigned short* __restrict__ fX,
    const unsigned short* __restrict__ gX,
    const float* __restrict__ w1,
    const float* __restrict__ b1v, const float* __restrict__ gammav,
    const float* __restrict__ betav, const float* __restrict__ rmeanv,
    const float* __restrict__ rvarv, const float* __restrict__ w2v,
    const float* __restrict__ b2v, float* __restrict__ out)
{
    __shared__ __align__(16) char smem[65536];   // epilogue u-reduction + head

    const int tid = threadIdx.x;
    const int w   = tid >> 6;        // 0..7
    const int h   = w >> 2;          // m-half
    const int q   = w & 3;           // n-chunk within TN=128
    const int l   = tid & 63;
    const int lm  = l & 15;
    const int lq  = l >> 4;
    const int b   = blockIdx.x & 7;
    const int m0  = (blockIdx.x >> 3) * 64;

    const unsigned short* fXb = fX + (size_t)b * NM * NC;
    const unsigned short* gXb = gX + (size_t)b * NC * NM;

    // Q fragments: this half's 2 m-tiles.
    short8 qf[2][4];
    {
        const int qt0 = (m0 >> 4) + h * 2;
        #pragma unroll
        for (int mt = 0; mt < 2; ++mt)
            #pragma unroll
            for (int ks = 0; ks < 4; ++ks)
                qf[mt][ks] = *(const short8*)
                    (fXb + (size_t)(qt0 + mt) * 4 * FRAG + ks * FRAG + l * 8);
    }

    // K stream: ktiles 8*it + 2q, 8*it + 2q+1.
    const unsigned short* kpA = fXb + (size_t)(2 * q) * 4 * FRAG + l * 8;
    const unsigned short* kpB = fXb + (size_t)(2 * q + 1) * 4 * FRAG + l * 8;
    // G stream: nblk = it, k2 = q, all 8 ot.
    const unsigned short* gp = gXb + (size_t)q * FRAG + l * 8;

    short8 kfA[4], kfB[4], gf[8];
    #pragma unroll
    for (int ks = 0; ks < 4; ++ks) {
        kfA[ks] = *(const short8*)(kpA + ks * FRAG);
        kfB[ks] = *(const short8*)(kpB + ks * FRAG);
    }
    #pragma unroll
    for (int ot = 0; ot < 8; ++ot)
        gf[ot] = *(const short8*)(gp + ot * 4 * FRAG);

    floatx4 u[2][8];
    float lsum[2] = {0.f, 0.f};
    #pragma unroll
    for (int mt = 0; mt < 2; ++mt)
        #pragma unroll
        for (int ot = 0; ot < 8; ++ot)
            u[mt][ot] = (floatx4){0.f, 0.f, 0.f, 0.f};

    for (int it = 0; it < 32; ++it) {
        // QK: sv[mt] = S[n-loc][m] for this wave's 32 n.
        floatx4 svA[2], svB[2];
        __builtin_amdgcn_s_setprio(1);
        #pragma unroll
        for (int mt = 0; mt < 2; ++mt) {
            floatx4 a  = {-24.f, -24.f, -24.f, -24.f};
            floatx4 bb = {-24.f, -24.f, -24.f, -24.f};
            #pragma unroll
            for (int ks = 0; ks < 4; ++ks) {
                a  = MFMA(kfA[ks], qf[mt][ks], a);
                bb = MFMA(kfB[ks], qf[mt][ks], bb);
            }
            svA[mt] = a; svB[mt] = bb;
        }
        __builtin_amdgcn_s_setprio(0);
        if (it < 31) {
            kpA += 8 * 4 * FRAG; kpB += 8 * 4 * FRAG;
            #pragma unroll
            for (int ks = 0; ks < 4; ++ks) {
                kfA[ks] = *(const short8*)(kpA + ks * FRAG);
                kfB[ks] = *(const short8*)(kpB + ks * FRAG);
            }
        }

        // softmax partial + in-register P fragment (pi-order matches gX).
        S8U pa[2];
        #pragma unroll
        for (int mt = 0; mt < 2; ++mt) {
            float pA0 = EXP2F(svA[mt][0]);
            float pA1 = EXP2F(svA[mt][1]);
            float pA2 = EXP2F(svA[mt][2]);
            float pA3 = EXP2F(svA[mt][3]);
            float pB0 = EXP2F(svB[mt][0]);
            float pB1 = EXP2F(svB[mt][1]);
            float pB2 = EXP2F(svB[mt][2]);
            float pB3 = EXP2F(svB[mt][3]);
            lsum[mt] += ((pA0 + pA1) + (pA2 + pA3)) +
                        ((pB0 + pB1) + (pB2 + pB3));
            pa[mt].u2[0] = make_uint2(cvt_pk_bf16(pA0, pA1),
                                      cvt_pk_bf16(pA2, pA3));
            pa[mt].u2[1] = make_uint2(cvt_pk_bf16(pB0, pB1),
                                      cvt_pk_bf16(pB2, pB3));
        }

        // PV: u[mt][ot] += P-chunk . g-chunk (all 16 chains independent).
        __builtin_amdgcn_s_setprio(1);
        #pragma unroll
        for (int ot = 0; ot < 8; ++ot) {
            u[0][ot] = MFMA(pa[0].v, gf[ot], u[0][ot]);
            u[1][ot] = MFMA(pa[1].v, gf[ot], u[1][ot]);
        }
        __builtin_amdgcn_s_setprio(0);
        if (it < 31) {
            gp += 32 * FRAG;
            #pragma unroll
            for (int ot = 0; ot < 8; ++ot)
                gf[ot] = *(const short8*)(gp + ot * 4 * FRAG);
        }
    }

    // ---- epilogue ----
    // lsum: reduce over lq groups (covers this wave's 32 n per row m=lm).
    #pragma unroll
    for (int mt = 0; mt < 2; ++mt) {
        lsum[mt] += __shfl_xor(lsum[mt], 16);
        lsum[mt] += __shfl_xor(lsum[mt], 32);
    }

    // u reduction across the 4 waves of each m-half; lane layouts identical,
    // so it's a pure per-lane sum. XOR-swizzle ot slot by sx to avoid bank
    // conflicts. red[w][lane][ot^sx] of floatx4.
    float* red = (float*)smem;
    const int sx = (l ^ (l >> 3)) & 7;
    floatx4 uS[2][2];
    #pragma unroll
    for (int mt = 0; mt < 2; ++mt) {
        if (mt) __syncthreads();
        float* dst = red + ((size_t)(w * 64 + l) * 32);
        #pragma unroll
        for (int ot = 0; ot < 8; ++ot)
            *(floatx4*)(dst + (ot ^ sx) * 4) = u[mt][ot];
        __syncthreads();
        #pragma unroll
        for (int j = 0; j < 2; ++j) {
            floatx4 s = {0.f, 0.f, 0.f, 0.f};
            #pragma unroll
            for (int wp = 0; wp < 4; ++wp)
                s += *(const floatx4*)(red + ((size_t)((h * 4 + wp) * 64 + l) * 32)
                                       + ((q * 2 + j) ^ sx) * 4);
            uS[mt][j] = s;
        }
    }
    __syncthreads();   // red dead; smem reused below

    float* lpartf = (float*)smem;            // [8][32]
    float* opartf = (float*)(smem + 2048);   // [8][32]

    if (lq == 0) {
        #pragma unroll
        for (int mt = 0; mt < 2; ++mt)
            lpartf[w * 32 + mt * 16 + lm] = lsum[mt];
    }

    // head: this wave's o-slice = q*32 + j*16 + lm, rows = half h.
    floatx4 hacc[2][2];
    {
        const float rs = RS_C;
        #pragma unroll
        for (int j = 0; j < 2; ++j) {
            int o = q * 32 + j * 16 + lm;
            short8 wf[4];
            #pragma unroll
            for (int ks = 0; ks < 4; ++ks) {
                const float* wp = w1 + (size_t)o * (2 * NC) + NC + ks * 32 + lq * 8;
                S8U t;
                t.u2[0] = make_uint2(pack2bf(wp[0] * rs, wp[1] * rs),
                                     pack2bf(wp[2] * rs, wp[3] * rs));
                t.u2[1] = make_uint2(pack2bf(wp[4] * rs, wp[5] * rs),
                                     pack2bf(wp[6] * rs, wp[7] * rs));
                wf[ks] = t.v;
            }
            #pragma unroll
            for (int mt = 0; mt < 2; ++mt) {
                floatx4 a = {0.f, 0.f, 0.f, 0.f};
                #pragma unroll
                for (int ks = 0; ks < 4; ++ks)
                    a = MFMA(qf[mt][ks], wf[ks], a);
                hacc[mt][j] = a;
            }
        }
    }
    __syncthreads();   // lpart visible

    float Abn[2], Dbn[2], W2[2];
    #pragma unroll
    for (int j = 0; j < 2; ++j) {
        int o = q * 32 + j * 16 + lm;
        float Ar = gammav[o] * rsqrtf(rvarv[o] + 1e-5f);
        Abn[j] = Ar;
        Dbn[j] = (b1v[o] - rmeanv[o]) * Ar + betav[o];
        W2[j]  = w2v[o];
    }
    float av[8];
    #pragma unroll
    for (int mt = 0; mt < 2; ++mt) {
        float4 Lt = make_float4(0.f, 0.f, 0.f, 0.f);
        #pragma unroll
        for (int wp = 0; wp < 4; ++wp) {
            float4 Lp = *(const float4*)
                &lpartf[(h * 4 + wp) * 32 + mt * 16 + lq * 4];
            Lt.x += Lp.x; Lt.y += Lp.y; Lt.z += Lp.z; Lt.w += Lp.w;
        }
        #pragma unroll
        for (int r = 0; r < 4; ++r) {
            float rl = 1.f / ((const float*)&Lt)[r];
            float t0 = Abn[0] * (uS[mt][0][r] * rl + hacc[mt][0][r]) + Dbn[0];
            float t1 = Abn[1] * (uS[mt][1][r] * rl + hacc[mt][1][r]) + Dbn[1];
            t0 = t0 >= 0.f ? t0 : 0.01f * t0;
            t1 = t1 >= 0.f ? t1 : 0.01f * t1;
            av[mt * 4 + r] = W2[0] * t0 + W2[1] * t1;
        }
    }
    #pragma unroll
    for (int i = 0; i < 8; ++i) {
        av[i] += __shfl_xor(av[i], 1);
        av[i] += __shfl_xor(av[i], 2);
        av[i] += __shfl_xor(av[i], 4);
        av[i] += __shfl_xor(av[i], 8);
    }
    if (lm == 0) {
        #pragma unroll
        for (int mt = 0; mt < 2; ++mt)
            #pragma unroll
            for (int r = 0; r < 4; ++r)
                opartf[w * 32 + mt * 16 + lq * 4 + r] = av[mt * 4 + r];
    }
    __syncthreads();
    if (tid < 64) {
        const int h2  = tid >> 5;
        const int r32 = tid & 31;
        out[(size_t)b * NM + m0 + tid] =
            b2v[0] + opartf[(h2 * 4 + 0) * 32 + r32]
                   + opartf[(h2 * 4 + 1) * 32 + r32]
                   + opartf[(h2 * 4 + 2) * 32 + r32]
                   + opartf[(h2 * 4 + 3) * 32 + r32];
    }
}

extern "C" void kernel_launch(void* const* d_in, const int* in_sizes, int n_in,
                              void* d_out, int out_size, void* d_ws, size_t ws_size,
                              hipStream_t stream) {
    const float* f     = (const float*)d_in[0];
    const float* w1    = (const float*)d_in[1];
    const float* b1    = (const float*)d_in[2];
    const float* gamma = (const float*)d_in[3];
    const float* beta  = (const float*)d_in[4];
    const float* rmean = (const float*)d_in[5];
    const float* rvar  = (const float*)d_in[6];
    const float* w2    = (const float*)d_in[7];
    const float* b2    = (const float*)d_in[8];
    float* out = (float*)d_out;

    unsigned short* fX = (unsigned short*)d_ws;              // 8 MB bf16 frag-order
    unsigned short* gX = fX + (size_t)NB * NM * NC;          // 8 MB bf16 frag-order

    hipLaunchKernelGGL(k_prep_f, dim3(512), dim3(256), 0, stream, f, fX);
    hipLaunchKernelGGL(k_prep_g, dim3(256), dim3(256), 0, stream, fX, w1, gX);
    hipLaunchKernelGGL(k_attn,   dim3(512), dim3(512), 0, stream,
                       fX, gX, w1, b1, gamma, beta, rmean, rvar, w2, b2, out);
}

// Round 9
// 156.909 us; speedup vs baseline: 1.1162x; 1.1162x over previous
//
#include <hip/hip_runtime.h>

#define NB 8
#define NC 128
#define NM 4096
#define FRAG 512   // shorts per (tile,ks) fragment block: 64 lanes x 8

typedef __attribute__((ext_vector_type(8))) short short8;
typedef __attribute__((ext_vector_type(4))) float floatx4;

#define MFMA(a, b, c) __builtin_amdgcn_mfma_f32_16x16x32_bf16(a, b, c, 0, 0, 0)
#define EXP2F(x) __builtin_amdgcn_exp2f(x)

union S8U { short8 v; uint2 u2[2]; };

__device__ __forceinline__ unsigned pack2bf(float a, float b) {
    unsigned ua = __float_as_uint(a);
    unsigned ub = __float_as_uint(b);
    ua += 0x7fffu + ((ua >> 16) & 1u);
    ub += 0x7fffu + ((ub >> 16) & 1u);
    return (ua >> 16) | (ub & 0xffff0000u);
}

// Single-instruction packed f32->bf16 (RNE), same rounding as pack2bf.
__device__ __forceinline__ unsigned cvt_pk_bf16(float a, float b) {
    unsigned r;
    asm("v_cvt_pk_bf16_f32 %0, %1, %2" : "=v"(r) : "v"(a), "v"(b));
    return r;
}

// QK softmax scale folded into fX: sqrt(2^-3.5 * log2(e)); RS = 1/SF.
__constant__ float SF_C = 0.35712442f;
__constant__ float RS_C = 2.8001530f;

// ---------------------------------------------------------------------------
// Fragment-order layouts (one contiguous 1024B chunk per wave fragment load):
//   fX[b][mt(256)][ks(4)][lane(64)][8] : lane l=(lq*16+lm) holds
//       f-row (mt*16+lm), cols ks*32+lq*8..+7, scaled by SF, bf16.
//   gX[b][nblk(32)][ot(8)][k2(4)][lane(64)][8] : lane l holds
//       g-row o=ot*16+lm, cols n=nblk*128+k2*32+lq*8..+7, bf16.
// ---------------------------------------------------------------------------

// P1: fX from f (transpose + scale + bf16 + fragment order)
__global__ __launch_bounds__(256) void k_prep_f(
    const float* __restrict__ f, unsigned short* __restrict__ fX)
{
    __shared__ float Ls[128][65];
    const int tid = threadIdx.x;
    const int b   = blockIdx.x & 7;
    const int m0  = (blockIdx.x >> 3) * 64;
    const float* fb = f + (size_t)b * NC * NM;
    #pragma unroll
    for (int k = 0; k < 32; ++k) {
        int idx = tid + k * 256;
        int c = idx >> 6, mm = idx & 63;
        Ls[c][mm] = fb[(size_t)c * NM + m0 + mm];
    }
    __syncthreads();
    const float sf = SF_C;
    const int m  = tid >> 2;
    const int ks = tid & 3;
    const int ch = ks * 32;
    unsigned pk[16];
    #pragma unroll
    for (int i = 0; i < 16; ++i)
        pk[i] = pack2bf(Ls[ch + 2 * i][m] * sf, Ls[ch + 2 * i + 1][m] * sf);
    const int Mg  = m0 + m;
    const int mt  = Mg >> 4;
    const int lmm = Mg & 15;
    unsigned short* dst = fX + ((size_t)b * 256 + mt) * 4 * FRAG + ks * FRAG;
    #pragma unroll
    for (int q = 0; q < 4; ++q)
        *(uint4*)(dst + (q * 16 + lmm) * 8) =
            make_uint4(pk[4 * q], pk[4 * q + 1], pk[4 * q + 2], pk[4 * q + 3]);
}

// ---------------------------------------------------------------------------
// P2 (MFMA): gX = bf16( (w1a*RS) . fX ) in fragment order.
// grid 256 = b(8) x nblk(32); 4 waves; wave wv owns ot = 2wv, 2wv+1.
// ---------------------------------------------------------------------------
__global__ __launch_bounds__(256) void k_prep_g(
    const unsigned short* __restrict__ fX, const float* __restrict__ w1,
    unsigned short* __restrict__ gX)
{
    __shared__ unsigned short gt[128][136];   // [o][n-local]
    const int tid = threadIdx.x;
    const int wv  = tid >> 6;
    const int l   = tid & 63;
    const int lm  = l & 15;
    const int lq  = l >> 4;
    const int b    = blockIdx.x & 7;
    const int nblk = blockIdx.x >> 3;

    const float rs = RS_C;

    short8 wf2[2][4];
    #pragma unroll
    for (int j = 0; j < 2; ++j) {
        const int o = (wv * 2 + j) * 16 + lm;
        #pragma unroll
        for (int ks = 0; ks < 4; ++ks) {
            const float* wp = w1 + (size_t)o * (2 * NC) + ks * 32 + lq * 8;
            S8U t;
            t.u2[0] = make_uint2(pack2bf(wp[0] * rs, wp[1] * rs),
                                 pack2bf(wp[2] * rs, wp[3] * rs));
            t.u2[1] = make_uint2(pack2bf(wp[4] * rs, wp[5] * rs),
                                 pack2bf(wp[6] * rs, wp[7] * rs));
            wf2[j][ks] = t.v;
        }
    }

    const unsigned short* fXb = fX + (size_t)b * NM * NC;
    #pragma unroll 2
    for (int nt = 0; nt < 8; ++nt) {
        short8 af[4];
        #pragma unroll
        for (int ks = 0; ks < 4; ++ks)
            af[ks] = *(const short8*)
                (fXb + (size_t)(nblk * 8 + nt) * 4 * FRAG + ks * FRAG + l * 8);
        #pragma unroll
        for (int j = 0; j < 2; ++j) {
            floatx4 D = {0.f, 0.f, 0.f, 0.f};
            #pragma unroll
            for (int ks = 0; ks < 4; ++ks)
                D = MFMA(af[ks], wf2[j][ks], D);
            *(uint2*)&gt[(wv * 2 + j) * 16 + lm][nt * 16 + lq * 4] =
                make_uint2(pack2bf(D[0], D[1]), pack2bf(D[2], D[3]));
        }
    }
    __syncthreads();

    #pragma unroll
    for (int j = 0; j < 2; ++j) {
        const int ot = wv * 2 + j;
        #pragma unroll
        for (int k2 = 0; k2 < 4; ++k2) {
            uint4 v = *(const uint4*)&gt[ot * 16 + lm][k2 * 32 + lq * 8];
            *(uint4*)(gX + (((size_t)b * 32 + nblk) * 8 + ot) * 4 * FRAG
                      + k2 * FRAG + l * 8) = v;
        }
    }
}

// ---------------------------------------------------------------------------
// Main: MFMA flash attention + fused cls head. Round-6 geometry (64 rows,
// TN=128/iter, 4 waves, grid 512) with PV-LAG-2 + Ps[4] + barrier every 2
// iterations: QK(it) -> Ps[it&3]; PV(it-2) reads Ps[(it-2)&3] (written two
// barrier intervals ago); barriers only at the end of EVEN iterations.
// gf stays a 2-slot ping-pong: PV(it-2) consumes slot it&1, which is then
// refilled with gf(it) for use at it+2 (load-use distance = 2 iters).
// 17 barriers total instead of 32. Epilogue lpart/opart alias Ps[0].
// ---------------------------------------------------------------------------
__global__ __launch_bounds__(256, 2) void k_attn(
    const unsigned short* __restrict__ fX,
    const unsigned short* __restrict__ gX,
    const float* __restrict__ w1,
    const float* __restrict__ b1v, const float* __restrict__ gammav,
    const float* __restrict__ betav, const float* __restrict__ rmeanv,
    const float* __restrict__ rvarv, const float* __restrict__ w2v,
    const float* __restrict__ b2v, float* __restrict__ out)
{
    __shared__ __align__(16) char Ps[4][16384];   // 64KB; [0] reused in epilogue

    const int tid = threadIdx.x;
    const int w   = tid >> 6;
    const int l   = tid & 63;
    const int lm  = l & 15;
    const int lq  = l >> 4;
    const int b   = blockIdx.x & 7;
    const int m0  = (blockIdx.x >> 3) * 64;

    // --- Ps addressing (fragment order + XOR swizzle), per-lane constant ---
    const int lq0 = lq & 1;
    const int lq1 = lq >> 1;
    const int lm3 = lm >> 3;
    const unsigned Xsw = (unsigned)(((lq1 << 1) | lm3) << 4);
    const unsigned wofsA =
        ((((unsigned)(w >> 1) * 4 * 16) + ((unsigned)(2 * (w & 1) + lq1) * 16)
          + (unsigned)lm) * 16 + (unsigned)(8 * lq0)) ^ Xsw;
    const unsigned rofs = ((unsigned)l * 16) ^ ((((unsigned)l >> 3) & 3u) << 4);

    const unsigned short* fXb = fX + (size_t)b * NM * NC;
    const unsigned short* gXb = gX + (size_t)b * NC * NM;

    short8 qf[4][4];
    {
        const int qt0 = m0 >> 4;
        #pragma unroll
        for (int mt = 0; mt < 4; ++mt)
            #pragma unroll
            for (int ks = 0; ks < 4; ++ks)
                qf[mt][ks] = *(const short8*)
                    (fXb + (size_t)(qt0 + mt) * 4 * FRAG + ks * FRAG + l * 8);
    }

    const unsigned short* kpA = fXb + (size_t)w * 4 * FRAG + l * 8;
    const unsigned short* kpB = fXb + (size_t)(4 + w) * 4 * FRAG + l * 8;
    const unsigned short* gp0 = gXb + (size_t)(2 * w) * 4 * FRAG + l * 8;
    const unsigned short* gp1 = gXb + (size_t)(2 * w + 1) * 4 * FRAG + l * 8;

    short8 kfA[4], kfB[4];
    short8 gA0[4], gA1[4], gB0[4], gB1[4];   // slot0 = gA (even gens), slot1 = gB (odd)
    #pragma unroll
    for (int ks = 0; ks < 4; ++ks) {
        kfA[ks] = *(const short8*)(kpA + ks * FRAG);
        kfB[ks] = *(const short8*)(kpB + ks * FRAG);
    }
    #pragma unroll
    for (int k2 = 0; k2 < 4; ++k2) {           // gA = gf(0)
        gA0[k2] = *(const short8*)(gp0 + k2 * FRAG);
        gA1[k2] = *(const short8*)(gp1 + k2 * FRAG);
    }
    gp0 += 8 * 4 * FRAG; gp1 += 8 * 4 * FRAG;
    #pragma unroll
    for (int k2 = 0; k2 < 4; ++k2) {           // gB = gf(1)
        gB0[k2] = *(const short8*)(gp0 + k2 * FRAG);
        gB1[k2] = *(const short8*)(gp1 + k2 * FRAG);
    }

    floatx4 u[4][2];
    float lsum[4] = {0.f, 0.f, 0.f, 0.f};
    #pragma unroll
    for (int mt = 0; mt < 4; ++mt) {
        u[mt][0] = (floatx4){0.f, 0.f, 0.f, 0.f};
        u[mt][1] = (floatx4){0.f, 0.f, 0.f, 0.f};
    }

    // QK(it) + kf advance + softmax-exp + write to psW.
    auto qksm = [&](char* psW, bool loadK) {
        floatx4 svA[4], svB[4];
        __builtin_amdgcn_s_setprio(1);
        #pragma unroll
        for (int mt = 0; mt < 4; ++mt) {
            floatx4 a = {-24.f, -24.f, -24.f, -24.f};
            floatx4 bb = {-24.f, -24.f, -24.f, -24.f};
            #pragma unroll
            for (int ks = 0; ks < 4; ++ks) {
                a  = MFMA(kfA[ks], qf[mt][ks], a);
                bb = MFMA(kfB[ks], qf[mt][ks], bb);
            }
            svA[mt] = a; svB[mt] = bb;
        }
        __builtin_amdgcn_s_setprio(0);
        if (loadK) {
            kpA += 8 * 4 * FRAG; kpB += 8 * 4 * FRAG;
            #pragma unroll
            for (int ks = 0; ks < 4; ++ks) {
                kfA[ks] = *(const short8*)(kpA + ks * FRAG);
                kfB[ks] = *(const short8*)(kpB + ks * FRAG);
            }
        }
        #pragma unroll
        for (int mt = 0; mt < 4; ++mt) {
            float pA0 = EXP2F(svA[mt][0]);
            float pA1 = EXP2F(svA[mt][1]);
            float pA2 = EXP2F(svA[mt][2]);
            float pA3 = EXP2F(svA[mt][3]);
            float pB0 = EXP2F(svB[mt][0]);
            float pB1 = EXP2F(svB[mt][1]);
            float pB2 = EXP2F(svB[mt][2]);
            float pB3 = EXP2F(svB[mt][3]);
            lsum[mt] += ((pA0 + pA1) + (pA2 + pA3)) +
                        ((pB0 + pB1) + (pB2 + pB3));
            *(uint2*)(psW + mt * 4096 + wofsA) =
                make_uint2(cvt_pk_bf16(pA0, pA1), cvt_pk_bf16(pA2, pA3));
            *(uint2*)(psW + mt * 4096 + wofsA + 2048) =
                make_uint2(cvt_pk_bf16(pB0, pB1), cvt_pk_bf16(pB2, pB3));
        }
    };
    // PV from psR with gf slot (g0,g1).
    auto pv = [&](char* psR, short8 (&g0)[4], short8 (&g1)[4]) {
        #pragma unroll
        for (int k2 = 0; k2 < 4; ++k2) {
            short8 pf[4];
            #pragma unroll
            for (int mt = 0; mt < 4; ++mt)
                pf[mt] = *(const short8*)(psR + mt * 4096 + k2 * 1024 + rofs);
            __builtin_amdgcn_s_setprio(1);
            #pragma unroll
            for (int mt = 0; mt < 4; ++mt) {
                u[mt][0] = MFMA(pf[mt], g0[k2], u[mt][0]);
                u[mt][1] = MFMA(pf[mt], g1[k2], u[mt][1]);
            }
            __builtin_amdgcn_s_setprio(0);
        }
    };
    // Refill a gf slot with the next generation for this slot (it += 2).
    auto gload = [&](short8 (&g0)[4], short8 (&g1)[4]) {
        gp0 += 8 * 4 * FRAG; gp1 += 8 * 4 * FRAG;
        #pragma unroll
        for (int k2 = 0; k2 < 4; ++k2) {
            g0[k2] = *(const short8*)(gp0 + k2 * FRAG);
            g1[k2] = *(const short8*)(gp1 + k2 * FRAG);
        }
    };

    // ---- prologue: it=0 (barrier: even), it=1 (no barrier) ----
    qksm(Ps[0], true);
    __syncthreads();
    qksm(Ps[1], true);

    // ---- its 2..29: 7 groups of 4; barrier after even its only ----
    for (int i = 0; i < 7; ++i) {
        qksm(Ps[2], true); pv(Ps[0], gA0, gA1); gload(gA0, gA1);  // it=4i+2
        __syncthreads();
        qksm(Ps[3], true); pv(Ps[1], gB0, gB1); gload(gB0, gB1);  // it=4i+3
        qksm(Ps[0], true); pv(Ps[2], gA0, gA1); gload(gA0, gA1);  // it=4i+4
        __syncthreads();
        qksm(Ps[1], true); pv(Ps[3], gB0, gB1); gload(gB0, gB1);  // it=4i+5
    }
    // it=30 (barrier), it=31 (no kf load)
    qksm(Ps[2], true); pv(Ps[0], gA0, gA1); gload(gA0, gA1);
    __syncthreads();
    qksm(Ps[3], false); pv(Ps[1], gB0, gB1); gload(gB0, gB1);
    __syncthreads();
    // ---- drain: PV(30) from Ps[2] (gf(30)=gA), PV(31) from Ps[3] (gf(31)=gB)
    pv(Ps[2], gA0, gA1);
    pv(Ps[3], gB0, gB1);

    // ---- epilogue (lpart/opart alias Ps[0], long dead for drain buffers) ----
    float* lpart = (float*)Ps;               // [4][64]
    float* opart = (float*)Ps + 256;         // [4][64]

    #pragma unroll
    for (int mt = 0; mt < 4; ++mt) {
        lsum[mt] += __shfl_xor(lsum[mt], 16);
        lsum[mt] += __shfl_xor(lsum[mt], 32);
    }
    if (lq == 0) {
        #pragma unroll
        for (int mt = 0; mt < 4; ++mt)
            lpart[w * 64 + mt * 16 + lm] = lsum[mt];
    }

    floatx4 hacc[4][2];
    {
        const float rs = RS_C;
        #pragma unroll
        for (int j = 0; j < 2; ++j) {
            int o = w * 32 + j * 16 + lm;
            short8 wf[4];
            #pragma unroll
            for (int ks = 0; ks < 4; ++ks) {
                const float* wp = w1 + (size_t)o * (2 * NC) + NC + ks * 32 + lq * 8;
                S8U t;
                t.u2[0] = make_uint2(pack2bf(wp[0] * rs, wp[1] * rs),
                                     pack2bf(wp[2] * rs, wp[3] * rs));
                t.u2[1] = make_uint2(pack2bf(wp[4] * rs, wp[5] * rs),
                                     pack2bf(wp[6] * rs, wp[7] * rs));
                wf[ks] = t.v;
            }
            #pragma unroll
            for (int mt = 0; mt < 4; ++mt) {
                floatx4 a = {0.f, 0.f, 0.f, 0.f};
                #pragma unroll
                for (int ks = 0; ks < 4; ++ks)
                    a = MFMA(qf[mt][ks], wf[ks], a);
                hacc[mt][j] = a;
            }
        }
    }
    __syncthreads();

    float Abn[2], Dbn[2], W2[2];
    #pragma unroll
    for (int j = 0; j < 2; ++j) {
        int o = w * 32 + j * 16 + lm;
        float Ar = gammav[o] * rsqrtf(rvarv[o] + 1e-5f);
        Abn[j] = Ar;
        Dbn[j] = (b1v[o] - rmeanv[o]) * Ar + betav[o];
        W2[j]  = w2v[o];
    }
    float av[16];
    #pragma unroll
    for (int mt = 0; mt < 4; ++mt) {
        float4 L0 = *(const float4*)&lpart[0 * 64 + mt * 16 + lq * 4];
        float4 L1 = *(const float4*)&lpart[1 * 64 + mt * 16 + lq * 4];
        float4 L2 = *(const float4*)&lpart[2 * 64 + mt * 16 + lq * 4];
        float4 L3 = *(const float4*)&lpart[3 * 64 + mt * 16 + lq * 4];
        float4 Lt;
        Lt.x = (L0.x + L1.x) + (L2.x + L3.x);
        Lt.y = (L0.y + L1.y) + (L2.y + L3.y);
        Lt.z = (L0.z + L1.z) + (L2.z + L3.z);
        Lt.w = (L0.w + L1.w) + (L2.w + L3.w);
        #pragma unroll
        for (int r = 0; r < 4; ++r) {
            float rl = 1.f / ((const float*)&Lt)[r];
            float t0 = Abn[0] * (u[mt][0][r] * rl + hacc[mt][0][r]) + Dbn[0];
            float t1 = Abn[1] * (u[mt][1][r] * rl + hacc[mt][1][r]) + Dbn[1];
            t0 = t0 >= 0.f ? t0 : 0.01f * t0;
            t1 = t1 >= 0.f ? t1 : 0.01f * t1;
            av[mt * 4 + r] = W2[0] * t0 + W2[1] * t1;
        }
    }
    #pragma unroll
    for (int i = 0; i < 16; ++i) {
        av[i] += __shfl_xor(av[i], 1);
        av[i] += __shfl_xor(av[i], 2);
        av[i] += __shfl_xor(av[i], 4);
        av[i] += __shfl_xor(av[i], 8);
    }
    if (lm == 0) {
        #pragma unroll
        for (int mt = 0; mt < 4; ++mt)
            #pragma unroll
            for (int r = 0; r < 4; ++r)
                opart[w * 64 + mt * 16 + lq * 4 + r] = av[mt * 4 + r];
    }
    __syncthreads();
    if (tid < 64)
        out[(size_t)b * NM + m0 + tid] =
            b2v[0] + opart[tid] + opart[64 + tid] +
            opart[128 + tid] + opart[192 + tid];
}

extern "C" void kernel_launch(void* const* d_in, const int* in_sizes, int n_in,
                              void* d_out, int out_size, void* d_ws, size_t ws_size,
                              hipStream_t stream) {
    const float* f     = (const float*)d_in[0];
    const float* w1    = (const float*)d_in[1];
    const float* b1    = (const float*)d_in[2];
    const float* gamma = (const float*)d_in[3];
    const float* beta  = (const float*)d_in[4];
    const float* rmean = (const float*)d_in[5];
    const float* rvar  = (const float*)d_in[6];
    const float* w2    = (const float*)d_in[7];
    const float* b2    = (const float*)d_in[8];
    float* out = (float*)d_out;

    unsigned short* fX = (unsigned short*)d_ws;              // 8 MB bf16 frag-order
    unsigned short* gX = fX + (size_t)NB * NM * NC;          // 8 MB bf16 frag-order

    hipLaunchKernelGGL(k_prep_f, dim3(512), dim3(256), 0, stream, f, fX);
    hipLaunchKernelGGL(k_prep_g, dim3(256), dim3(256), 0, stream, fX, w1, gX);
    hipLaunchKernelGGL(k_attn,   dim3(512), dim3(256), 0, stream,
                       fX, gX, w1, b1, gamma, beta, rmean, rvar, w2, b2, out);
}

// Round 10
// 152.819 us; speedup vs baseline: 1.1461x; 1.0268x over previous
//
#include <hip/hip_runtime.h>

#define NB 8
#define NC 128
#define NM 4096
#define FRAG 512   // shorts per (tile,ks) fragment block: 64 lanes x 8

typedef __attribute__((ext_vector_type(8))) short short8;
typedef __attribute__((ext_vector_type(4))) float floatx4;

#define MFMA(a, b, c) __builtin_amdgcn_mfma_f32_16x16x32_bf16(a, b, c, 0, 0, 0)
#define EXP2F(x) __builtin_amdgcn_exp2f(x)

union S8U { short8 v; uint2 u2[2]; };

__device__ __forceinline__ unsigned pack2bf(float a, float b) {
    unsigned ua = __float_as_uint(a);
    unsigned ub = __float_as_uint(b);
    ua += 0x7fffu + ((ua >> 16) & 1u);
    ub += 0x7fffu + ((ub >> 16) & 1u);
    return (ua >> 16) | (ub & 0xffff0000u);
}

// Single-instruction packed f32->bf16 (RNE), same rounding as pack2bf.
__device__ __forceinline__ unsigned cvt_pk_bf16(float a, float b) {
    unsigned r;
    asm("v_cvt_pk_bf16_f32 %0, %1, %2" : "=v"(r) : "v"(a), "v"(b));
    return r;
}

// QK softmax scale folded into fX: sqrt(2^-3.5 * log2(e)); RS = 1/SF.
__constant__ float SF_C = 0.35712442f;
__constant__ float RS_C = 2.8001530f;

// ---------------------------------------------------------------------------
// Fragment-order layouts (one contiguous 1024B chunk per wave fragment load):
//   fX[b][mt(256)][ks(4)][lane(64)][8] : lane l=(lq*16+lm) holds
//       f-row (mt*16+lm), cols ks*32+lq*8..+7, scaled by SF, bf16.
//   gX[b][nblk(32)][ot(8)][k2(4)][lane(64)][8] : lane l holds
//       g-row o=ot*16+lm, cols n=nblk*128+k2*32+lq*8..+7, bf16.
// ---------------------------------------------------------------------------

// FUSED prep: per block (b, chunk of 64 indices): stage f -> fX fragments
// (global) + LsT (LDS bf16 transposed copy) -> MFMA g = (w1a*RS).f for the
// same 64 indices as n -> gX fragments. Replaces the old 2-kernel pipeline
// (prep_g was 1 block/CU latency-bound and re-read fX from global).
// chunk <-> (nblk = chunk>>1, k2pair = (chunk&1)*2): exact cover of gX.
// grid 512 = b(8) x chunk(64); 256 threads; ~50 KB LDS -> 2 blocks/CU.
__global__ __launch_bounds__(256) void k_prep(
    const float* __restrict__ f, const float* __restrict__ w1,
    unsigned short* __restrict__ fX, unsigned short* __restrict__ gX)
{
    __shared__ __align__(16) char smem[50176];
    float (*Ls)[65] = (float (*)[65])smem;                         // 128x65 f32
    unsigned short (*LsT)[132] =
        (unsigned short (*)[132])(smem + 33280);                   // 64x132 bf16
    unsigned short (*gt2)[72] = (unsigned short (*)[72])smem;      // aliases Ls

    const int tid   = threadIdx.x;
    const int b     = blockIdx.x & 7;
    const int chunk = blockIdx.x >> 3;
    const int m0    = chunk * 64;
    const float* fb = f + (size_t)b * NC * NM;
    #pragma unroll
    for (int k = 0; k < 32; ++k) {
        int idx = tid + k * 256;
        int c = idx >> 6, mm = idx & 63;
        Ls[c][mm] = fb[(size_t)c * NM + m0 + mm];
    }
    __syncthreads();

    const float sf = SF_C;
    const int m  = tid >> 2;     // 0..63 (local index)
    const int ks = tid & 3;
    const int ch = ks * 32;
    unsigned pk[16];
    #pragma unroll
    for (int i = 0; i < 16; ++i)
        pk[i] = pack2bf(Ls[ch + 2 * i][m] * sf, Ls[ch + 2 * i + 1][m] * sf);
    {   // global fX fragments (bit-identical to the old k_prep_f)
        const int Mg  = m0 + m;
        const int mt  = Mg >> 4;
        const int lmm = Mg & 15;
        unsigned short* dst = fX + ((size_t)b * 256 + mt) * 4 * FRAG + ks * FRAG;
        #pragma unroll
        for (int q = 0; q < 4; ++q)
            *(uint4*)(dst + (q * 16 + lmm) * 8) =
                make_uint4(pk[4 * q], pk[4 * q + 1], pk[4 * q + 2], pk[4 * q + 3]);
    }
    // LDS transposed bf16 copy (same packed bits), row m, cols ch..ch+31
    #pragma unroll
    for (int q = 0; q < 4; ++q)
        *(uint4*)&LsT[m][ks * 32 + q * 8] =
            make_uint4(pk[4 * q], pk[4 * q + 1], pk[4 * q + 2], pk[4 * q + 3]);
    __syncthreads();

    // ---- GEMM: g[o][n-local] for n-local = 64 chunk indices ----
    const int wv = tid >> 6;
    const int l  = tid & 63;
    const int lm = l & 15;
    const int lq = l >> 4;
    const float rs = RS_C;

    short8 wf2[2][4];
    #pragma unroll
    for (int j = 0; j < 2; ++j) {
        const int o = (wv * 2 + j) * 16 + lm;
        #pragma unroll
        for (int kk = 0; kk < 4; ++kk) {
            const float* wp = w1 + (size_t)o * (2 * NC) + kk * 32 + lq * 8;
            S8U t;
            t.u2[0] = make_uint2(pack2bf(wp[0] * rs, wp[1] * rs),
                                 pack2bf(wp[2] * rs, wp[3] * rs));
            t.u2[1] = make_uint2(pack2bf(wp[4] * rs, wp[5] * rs),
                                 pack2bf(wp[6] * rs, wp[7] * rs));
            wf2[j][kk] = t.v;
        }
    }
    #pragma unroll
    for (int nt = 0; nt < 4; ++nt) {
        short8 af[4];
        #pragma unroll
        for (int kk = 0; kk < 4; ++kk)
            af[kk] = *(const short8*)&LsT[nt * 16 + lm][kk * 32 + lq * 8];
        #pragma unroll
        for (int j = 0; j < 2; ++j) {
            floatx4 D = {0.f, 0.f, 0.f, 0.f};
            #pragma unroll
            for (int kk = 0; kk < 4; ++kk)
                D = MFMA(af[kk], wf2[j][kk], D);
            *(uint2*)&gt2[(wv * 2 + j) * 16 + lm][nt * 16 + lq * 4] =
                make_uint2(pack2bf(D[0], D[1]), pack2bf(D[2], D[3]));
        }
    }
    __syncthreads();

    // ---- gX fragment store: this chunk's (nblk, k2pair) ----
    const int nblk = chunk >> 1;
    const int k2b  = (chunk & 1) * 2;
    #pragma unroll
    for (int j = 0; j < 2; ++j) {
        const int ot = wv * 2 + j;
        #pragma unroll
        for (int k2l = 0; k2l < 2; ++k2l) {
            uint4 v = *(const uint4*)&gt2[ot * 16 + lm][k2l * 32 + lq * 8];
            *(uint4*)(gX + (((size_t)b * 32 + nblk) * 8 + ot) * 4 * FRAG
                      + (k2b + k2l) * FRAG + l * 8) = v;
        }
    }
}

// ---------------------------------------------------------------------------
// Main: MFMA flash attention + fused cls head. ROUND-6 CHAMPION, verbatim:
// PV-lag-1 pipeline (QK(it) -> Ps[it&1]; PV(it-1) from Ps[(it-1)&1]), one
// __syncthreads per iter, setprio around MFMA clusters, gf register
// ping-pong. grid 512 = b(8) x mblock(64); 4 waves, 2 blocks/CU.
// ---------------------------------------------------------------------------
__global__ __launch_bounds__(256, 2) void k_attn(
    const unsigned short* __restrict__ fX,
    const unsigned short* __restrict__ gX,
    const float* __restrict__ w1,
    const float* __restrict__ b1v, const float* __restrict__ gammav,
    const float* __restrict__ betav, const float* __restrict__ rmeanv,
    const float* __restrict__ rvarv, const float* __restrict__ w2v,
    const float* __restrict__ b2v, float* __restrict__ out)
{
    __shared__ __align__(16) char Ps[2][16384];
    __shared__ float lpart[4][64];
    __shared__ float opart[4][64];

    const int tid = threadIdx.x;
    const int w   = tid >> 6;
    const int l   = tid & 63;
    const int lm  = l & 15;
    const int lq  = l >> 4;
    const int b   = blockIdx.x & 7;
    const int m0  = (blockIdx.x >> 3) * 64;

    // --- Ps addressing (fragment order + XOR swizzle), per-lane constant ---
    const int lq0 = lq & 1;
    const int lq1 = lq >> 1;
    const int lm3 = lm >> 3;
    const unsigned Xsw = (unsigned)(((lq1 << 1) | lm3) << 4);
    const unsigned wofsA =
        ((((unsigned)(w >> 1) * 4 * 16) + ((unsigned)(2 * (w & 1) + lq1) * 16)
          + (unsigned)lm) * 16 + (unsigned)(8 * lq0)) ^ Xsw;
    const unsigned rofs = ((unsigned)l * 16) ^ ((((unsigned)l >> 3) & 3u) << 4);

    const unsigned short* fXb = fX + (size_t)b * NM * NC;
    const unsigned short* gXb = gX + (size_t)b * NC * NM;

    short8 qf[4][4];
    {
        const int qt0 = m0 >> 4;
        #pragma unroll
        for (int mt = 0; mt < 4; ++mt)
            #pragma unroll
            for (int ks = 0; ks < 4; ++ks)
                qf[mt][ks] = *(const short8*)
                    (fXb + (size_t)(qt0 + mt) * 4 * FRAG + ks * FRAG + l * 8);
    }

    const unsigned short* kpA = fXb + (size_t)w * 4 * FRAG + l * 8;
    const unsigned short* kpB = fXb + (size_t)(4 + w) * 4 * FRAG + l * 8;
    const unsigned short* gp0 = gXb + (size_t)(2 * w) * 4 * FRAG + l * 8;
    const unsigned short* gp1 = gXb + (size_t)(2 * w + 1) * 4 * FRAG + l * 8;

    short8 kfA[4], kfB[4];
    short8 gA0[4], gA1[4], gB0[4], gB1[4];
    #pragma unroll
    for (int ks = 0; ks < 4; ++ks) {
        kfA[ks] = *(const short8*)(kpA + ks * FRAG);
        kfB[ks] = *(const short8*)(kpB + ks * FRAG);
    }
    #pragma unroll
    for (int k2 = 0; k2 < 4; ++k2) {           // gA = gf(0)
        gA0[k2] = *(const short8*)(gp0 + k2 * FRAG);
        gA1[k2] = *(const short8*)(gp1 + k2 * FRAG);
    }

    floatx4 u[4][2];
    float lsum[4] = {0.f, 0.f, 0.f, 0.f};
    #pragma unroll
    for (int mt = 0; mt < 4; ++mt) {
        u[mt][0] = (floatx4){0.f, 0.f, 0.f, 0.f};
        u[mt][1] = (floatx4){0.f, 0.f, 0.f, 0.f};
    }

    // ---- prologue: it = 0 -> QK(0), exp2, write Ps[0], barrier ----
    {
        floatx4 svA[4], svB[4];
        __builtin_amdgcn_s_setprio(1);
        #pragma unroll
        for (int mt = 0; mt < 4; ++mt) {
            floatx4 a = {-24.f, -24.f, -24.f, -24.f};
            floatx4 bb = {-24.f, -24.f, -24.f, -24.f};
            #pragma unroll
            for (int ks = 0; ks < 4; ++ks) {
                a  = MFMA(kfA[ks], qf[mt][ks], a);
                bb = MFMA(kfB[ks], qf[mt][ks], bb);
            }
            svA[mt] = a; svB[mt] = bb;
        }
        __builtin_amdgcn_s_setprio(0);
        kpA += 8 * 4 * FRAG; kpB += 8 * 4 * FRAG;   // kf -> kf(1)
        #pragma unroll
        for (int ks = 0; ks < 4; ++ks) {
            kfA[ks] = *(const short8*)(kpA + ks * FRAG);
            kfB[ks] = *(const short8*)(kpB + ks * FRAG);
        }
        char* psb = Ps[0];
        #pragma unroll
        for (int mt = 0; mt < 4; ++mt) {
            float pA0 = EXP2F(svA[mt][0]);
            float pA1 = EXP2F(svA[mt][1]);
            float pA2 = EXP2F(svA[mt][2]);
            float pA3 = EXP2F(svA[mt][3]);
            float pB0 = EXP2F(svB[mt][0]);
            float pB1 = EXP2F(svB[mt][1]);
            float pB2 = EXP2F(svB[mt][2]);
            float pB3 = EXP2F(svB[mt][3]);
            lsum[mt] += ((pA0 + pA1) + (pA2 + pA3)) +
                        ((pB0 + pB1) + (pB2 + pB3));
            *(uint2*)(psb + mt * 4096 + wofsA) =
                make_uint2(cvt_pk_bf16(pA0, pA1), cvt_pk_bf16(pA2, pA3));
            *(uint2*)(psb + mt * 4096 + wofsA + 2048) =
                make_uint2(cvt_pk_bf16(pB0, pB1), cvt_pk_bf16(pB2, pB3));
        }
        __syncthreads();
    }

    // Body for iter IT (1..31): QK(IT) -> Ps[psW]; PV(IT-1) from Ps[psR]
    // with gC; prefetch kf(IT+1) (if LOADK) and gf(IT) into gN.
    auto body = [&](char* psW, char* psR,
                    short8 (&gC0)[4], short8 (&gC1)[4],
                    short8 (&gN0)[4], short8 (&gN1)[4], bool loadK) {
        floatx4 svA[4], svB[4];
        __builtin_amdgcn_s_setprio(1);
        #pragma unroll
        for (int mt = 0; mt < 4; ++mt) {
            floatx4 a = {-24.f, -24.f, -24.f, -24.f};
            floatx4 bb = {-24.f, -24.f, -24.f, -24.f};
            #pragma unroll
            for (int ks = 0; ks < 4; ++ks) {
                a  = MFMA(kfA[ks], qf[mt][ks], a);
                bb = MFMA(kfB[ks], qf[mt][ks], bb);
            }
            svA[mt] = a; svB[mt] = bb;
        }
        __builtin_amdgcn_s_setprio(0);
        if (loadK) {
            kpA += 8 * 4 * FRAG; kpB += 8 * 4 * FRAG;
            #pragma unroll
            for (int ks = 0; ks < 4; ++ks) {
                kfA[ks] = *(const short8*)(kpA + ks * FRAG);
                kfB[ks] = *(const short8*)(kpB + ks * FRAG);
            }
        }
        gp0 += 8 * 4 * FRAG; gp1 += 8 * 4 * FRAG;   // gf(IT)
        #pragma unroll
        for (int k2 = 0; k2 < 4; ++k2) {
            gN0[k2] = *(const short8*)(gp0 + k2 * FRAG);
            gN1[k2] = *(const short8*)(gp1 + k2 * FRAG);
        }
        #pragma unroll
        for (int mt = 0; mt < 4; ++mt) {
            float pA0 = EXP2F(svA[mt][0]);
            float pA1 = EXP2F(svA[mt][1]);
            float pA2 = EXP2F(svA[mt][2]);
            float pA3 = EXP2F(svA[mt][3]);
            float pB0 = EXP2F(svB[mt][0]);
            float pB1 = EXP2F(svB[mt][1]);
            float pB2 = EXP2F(svB[mt][2]);
            float pB3 = EXP2F(svB[mt][3]);
            lsum[mt] += ((pA0 + pA1) + (pA2 + pA3)) +
                        ((pB0 + pB1) + (pB2 + pB3));
            *(uint2*)(psW + mt * 4096 + wofsA) =
                make_uint2(cvt_pk_bf16(pA0, pA1), cvt_pk_bf16(pA2, pA3));
            *(uint2*)(psW + mt * 4096 + wofsA + 2048) =
                make_uint2(cvt_pk_bf16(pB0, pB1), cvt_pk_bf16(pB2, pB3));
        }
        // PV(IT-1): Ps[psR] ready since the previous barrier.
        #pragma unroll
        for (int k2 = 0; k2 < 4; ++k2) {
            short8 pf[4];
            #pragma unroll
            for (int mt = 0; mt < 4; ++mt)
                pf[mt] = *(const short8*)(psR + mt * 4096 + k2 * 1024 + rofs);
            __builtin_amdgcn_s_setprio(1);
            #pragma unroll
            for (int mt = 0; mt < 4; ++mt) {
                u[mt][0] = MFMA(pf[mt], gC0[k2], u[mt][0]);
                u[mt][1] = MFMA(pf[mt], gC1[k2], u[mt][1]);
            }
            __builtin_amdgcn_s_setprio(0);
        }
        __syncthreads();
    };

    // it = 1..30 (15 odd/even pairs), then it = 31 (no kf prefetch).
    for (int i = 0; i < 15; ++i) {
        body(Ps[1], Ps[0], gA0, gA1, gB0, gB1, true);   // odd it: C=gA, N=gB
        body(Ps[0], Ps[1], gB0, gB1, gA0, gA1, true);   // even it: C=gB, N=gA
    }
    body(Ps[1], Ps[0], gA0, gA1, gB0, gB1, false);      // it=31: gB <- gf(31)

    // ---- drain: PV(31) from Ps[1] with gB ----
    #pragma unroll
    for (int k2 = 0; k2 < 4; ++k2) {
        short8 pf[4];
        #pragma unroll
        for (int mt = 0; mt < 4; ++mt)
            pf[mt] = *(const short8*)(Ps[1] + mt * 4096 + k2 * 1024 + rofs);
        __builtin_amdgcn_s_setprio(1);
        #pragma unroll
        for (int mt = 0; mt < 4; ++mt) {
            u[mt][0] = MFMA(pf[mt], gB0[k2], u[mt][0]);
            u[mt][1] = MFMA(pf[mt], gB1[k2], u[mt][1]);
        }
        __builtin_amdgcn_s_setprio(0);
    }

    #pragma unroll
    for (int mt = 0; mt < 4; ++mt) {
        lsum[mt] += __shfl_xor(lsum[mt], 16);
        lsum[mt] += __shfl_xor(lsum[mt], 32);
    }
    if (lq == 0) {
        #pragma unroll
        for (int mt = 0; mt < 4; ++mt)
            lpart[w][mt * 16 + lm] = lsum[mt];
    }

    floatx4 hacc[4][2];
    {
        const float rs = RS_C;
        #pragma unroll
        for (int j = 0; j < 2; ++j) {
            int o = w * 32 + j * 16 + lm;
            short8 wf[4];
            #pragma unroll
            for (int ks = 0; ks < 4; ++ks) {
                const float* wp = w1 + (size_t)o * (2 * NC) + NC + ks * 32 + lq * 8;
                S8U t;
                t.u2[0] = make_uint2(pack2bf(wp[0] * rs, wp[1] * rs),
                                     pack2bf(wp[2] * rs, wp[3] * rs));
                t.u2[1] = make_uint2(pack2bf(wp[4] * rs, wp[5] * rs),
                                     pack2bf(wp[6] * rs, wp[7] * rs));
                wf[ks] = t.v;
            }
            #pragma unroll
            for (int mt = 0; mt < 4; ++mt) {
                floatx4 a = {0.f, 0.f, 0.f, 0.f};
                #pragma unroll
                for (int ks = 0; ks < 4; ++ks)
                    a = MFMA(qf[mt][ks], wf[ks], a);
                hacc[mt][j] = a;
            }
        }
    }
    __syncthreads();

    float Abn[2], Dbn[2], W2[2];
    #pragma unroll
    for (int j = 0; j < 2; ++j) {
        int o = w * 32 + j * 16 + lm;
        float Ar = gammav[o] * rsqrtf(rvarv[o] + 1e-5f);
        Abn[j] = Ar;
        Dbn[j] = (b1v[o] - rmeanv[o]) * Ar + betav[o];
        W2[j]  = w2v[o];
    }
    float av[16];
    #pragma unroll
    for (int mt = 0; mt < 4; ++mt) {
        float4 L0 = *(const float4*)&lpart[0][mt * 16 + lq * 4];
        float4 L1 = *(const float4*)&lpart[1][mt * 16 + lq * 4];
        float4 L2 = *(const float4*)&lpart[2][mt * 16 + lq * 4];
        float4 L3 = *(const float4*)&lpart[3][mt * 16 + lq * 4];
        float4 Lt;
        Lt.x = (L0.x + L1.x) + (L2.x + L3.x);
        Lt.y = (L0.y + L1.y) + (L2.y + L3.y);
        Lt.z = (L0.z + L1.z) + (L2.z + L3.z);
        Lt.w = (L0.w + L1.w) + (L2.w + L3.w);
        #pragma unroll
        for (int r = 0; r < 4; ++r) {
            float rl = 1.f / ((const float*)&Lt)[r];
            float t0 = Abn[0] * (u[mt][0][r] * rl + hacc[mt][0][r]) + Dbn[0];
            float t1 = Abn[1] * (u[mt][1][r] * rl + hacc[mt][1][r]) + Dbn[1];
            t0 = t0 >= 0.f ? t0 : 0.01f * t0;
            t1 = t1 >= 0.f ? t1 : 0.01f * t1;
            av[mt * 4 + r] = W2[0] * t0 + W2[1] * t1;
        }
    }
    #pragma unroll
    for (int i = 0; i < 16; ++i) {
        av[i] += __shfl_xor(av[i], 1);
        av[i] += __shfl_xor(av[i], 2);
        av[i] += __shfl_xor(av[i], 4);
        av[i] += __shfl_xor(av[i], 8);
    }
    if (lm == 0) {
        #pragma unroll
        for (int mt = 0; mt < 4; ++mt)
            #pragma unroll
            for (int r = 0; r < 4; ++r)
                opart[w][mt * 16 + lq * 4 + r] = av[mt * 4 + r];
    }
    __syncthreads();
    if (tid < 64)
        out[(size_t)b * NM + m0 + tid] =
            b2v[0] + opart[0][tid] + opart[1][tid] + opart[2][tid] + opart[3][tid];
}

extern "C" void kernel_launch(void* const* d_in, const int* in_sizes, int n_in,
                              void* d_out, int out_size, void* d_ws, size_t ws_size,
                              hipStream_t stream) {
    const float* f     = (const float*)d_in[0];
    const float* w1    = (const float*)d_in[1];
    const float* b1    = (const float*)d_in[2];
    const float* gamma = (const float*)d_in[3];
    const float* beta  = (const float*)d_in[4];
    const float* rmean = (const float*)d_in[5];
    const float* rvar  = (const float*)d_in[6];
    const float* w2    = (const float*)d_in[7];
    const float* b2    = (const float*)d_in[8];
    float* out = (float*)d_out;

    unsigned short* fX = (unsigned short*)d_ws;              // 8 MB bf16 frag-order
    unsigned short* gX = fX + (size_t)NB * NM * NC;          // 8 MB bf16 frag-order

    hipLaunchKernelGGL(k_prep, dim3(512), dim3(256), 0, stream, f, w1, fX, gX);
    hipLaunchKernelGGL(k_attn, dim3(512), dim3(256), 0, stream,
                       fX, gX, w1, b1, gamma, beta, rmean, rvar, w2, b2, out);
}